// Round 10
// baseline (808.475 us; speedup 1.0000x reference)
//
#include <hip/hip_runtime.h>
#include <hip/hip_bf16.h>

// Problem constants (match reference)
constexpr int B = 8192;
constexpr int G = 1024;
constexpr int E = 256;
constexpr int K = 2048;
constexpr float P_NULL = 0.1f;
constexpr int N_STEP = 4;

typedef unsigned short u16;
typedef short bf16x8 __attribute__((ext_vector_type(8)));
typedef float f32x4 __attribute__((ext_vector_type(4)));

// ---------------------------------------------------------------------------
// bf16 <-> f32 (RNE)
// ---------------------------------------------------------------------------
__device__ inline u16 f2bf(float f) {
    union { float f; uint32_t u; } cv;
    cv.f = f;
    const uint32_t u = cv.u;
    return (u16)((u + 0x7fffu + ((u >> 16) & 1u)) >> 16);
}
__device__ inline float bf2f(u16 h) {
    union { uint32_t u; float f; } cv;
    cv.u = ((uint32_t)h) << 16;
    return cv.f;
}
__device__ inline uint4 pack8(const float* v) {
    uint4 u;
    u.x = (uint32_t)f2bf(v[0]) | ((uint32_t)f2bf(v[1]) << 16);
    u.y = (uint32_t)f2bf(v[2]) | ((uint32_t)f2bf(v[3]) << 16);
    u.z = (uint32_t)f2bf(v[4]) | ((uint32_t)f2bf(v[5]) << 16);
    u.w = (uint32_t)f2bf(v[6]) | ((uint32_t)f2bf(v[7]) << 16);
    return u;
}

// async global->LDS, 16B per lane (LDS dest is lane-linear; global src is
// per-lane and may be permuted -> XOR-swizzle is applied on the GLOBAL side)
typedef __attribute__((address_space(1))) const void* gaddr_t;
typedef __attribute__((address_space(3))) void* laddr_t;
__device__ inline void gload_lds16(const void* g, void* l) {
    __builtin_amdgcn_global_load_lds((gaddr_t)g, (laddr_t)l, 16, 0, 0);
}

// XCD-aware tile swizzle (requires gridDim.y % 8 == 0)
__device__ inline void swizzle_tiles(int& tr, int& tc) {
    const int cx = gridDim.x, cy = gridDim.y;
    const int id = blockIdx.y * cx + blockIdx.x;
    const int k = id & 7;
    const int q = id >> 3;
    tr = k * (cy >> 3) + q / cx;
    tc = q % cx;
}

// ---------------------------------------------------------------------------
// Reduction helpers (256-thread blocks, wave64)
// ---------------------------------------------------------------------------
__device__ inline float wave_sum(float v) {
#pragma unroll
    for (int off = 32; off > 0; off >>= 1) v += __shfl_down(v, off, 64);
    return v;
}
__device__ inline float block_sum256(float v, float* sm) {
    v = wave_sum(v);
    const int w = threadIdx.x >> 6;
    if ((threadIdx.x & 63) == 0) sm[w] = v;
    __syncthreads();
    const float r = sm[0] + sm[1] + sm[2] + sm[3];
    __syncthreads();
    return r;
}

// ---------------------------------------------------------------------------
// f32 -> bf16 flat convert, 8 elems/thread
// ---------------------------------------------------------------------------
__global__ __launch_bounds__(256) void f2bf_kernel(
    const float* __restrict__ in, u16* __restrict__ out, int n) {
    const int i = (blockIdx.x * 256 + threadIdx.x) * 8;
    if (i + 7 >= n) {
        for (int j = i; j < n; ++j) out[j] = f2bf(in[j]);
        return;
    }
    const float4 a = *(const float4*)(in + i);
    const float4 b = *(const float4*)(in + i + 4);
    float v[8] = {a.x, a.y, a.z, a.w, b.x, b.y, b.z, b.w};
    *(uint4*)(out + i) = pack8(v);
}

// ---------------------------------------------------------------------------
// Fused prep: f32 (R,C) -> bf16 (R,C) copy + bf16 (C,R) transpose +
// csq[c] += (1/R) sum_r v^2.  grid (C/32, R/32), block 256.
// ---------------------------------------------------------------------------
__global__ __launch_bounds__(256) void prep_kernel(
    const float* __restrict__ in, u16* __restrict__ outN,
    u16* __restrict__ outT, float* __restrict__ csq, int R, int C,
    float inv_R) {
    __shared__ float tile[32][33];
    __shared__ float sred[8][32];
    const int bx = blockIdx.x * 32, by = blockIdx.y * 32;
    const int x = threadIdx.x & 31, y0 = threadIdx.x >> 5;
    float s = 0.f;
#pragma unroll
    for (int yy = 0; yy < 32; yy += 8) {
        const float v = in[(size_t)(by + y0 + yy) * C + bx + x];
        tile[y0 + yy][x] = v;
        outN[(size_t)(by + y0 + yy) * C + bx + x] = f2bf(v);
        s = fmaf(v, v, s);
    }
    sred[y0][x] = s;
    __syncthreads();
#pragma unroll
    for (int yy = 0; yy < 32; yy += 8)
        outT[(size_t)(bx + y0 + yy) * R + by + x] = f2bf(tile[x][y0 + yy]);
    if (y0 == 0) {
        float t = 0.f;
#pragma unroll
        for (int k2 = 0; k2 < 8; ++k2) t += sred[k2][x];
        atomicAdd(csq + bx + x, t * inv_R);
    }
}

// ---------------------------------------------------------------------------
// MFMA bf16 GEMM (128x128 tile, BK=64): acc = A(M,Kd) x Bm(N,Kd)^T
// Main-loop LDS XOR-swizzled (16B group g of row r at g^(r&7), applied on the
// GLOBAL source address) -> 0 bank conflicts (verified R7).
// Epilogues (all normalizers commute through row-linear GEMMs; exp is
// overflow-safe: logits provably in [-0.1, 0.1]):
//   EPI_U:  u = exp(alpha*acc - bias[col]) -> bf16 Cout (LDS-vectorized);
//           Saux[row] += row-sum(u)  (atomic)
//   EPI_WZ: w = e[row,col]*exp(alpha*acc - bias[col]) (e = Paux, unnormalized
//           encode weights; 1/S_enc cancels in w/Sum(w)); w tile kept in LDS
//           ONLY; Saux[row] += row-sum(w); then PHASE-2 computes
//           Zacc(row,0:256) += w_tile @ Xb2[:, k-slice]^T via f32 atomics.
//           w never touches HBM.
//   EPI_LOSS: D = P_NULL*exp(bias[row]) + Saux[row];
//             loss[row] += (1/N)*sum_col (acc/D - X[row,col])^2
// ---------------------------------------------------------------------------
enum { EPI_LOSS = 2, EPI_U = 4, EPI_WZ = 5 };

template <int EPI>
__global__ __launch_bounds__(256) void mfma_gemm_kernel(
    const u16* __restrict__ A, const u16* __restrict__ Bm,
    void* __restrict__ Cout, const float* __restrict__ bias,
    const float* __restrict__ X, const u16* __restrict__ Paux,
    float* __restrict__ Saux, float* __restrict__ Zacc,
    const u16* __restrict__ Xb2, int M, int N, int Kd, float alpha) {
    __shared__ u16 smem[16384];  // As | Bs during K-loop; 128x128 tile after
    u16* As = smem;
    u16* Bs = smem + 8192;
    const int tid = threadIdx.x;
    int btr, btc;
    swizzle_tiles(btr, btc);
    const int row0 = btr * 128, col0 = btc * 128;
    const int lane = tid & 63, wave = tid >> 6;
    const int wr = (wave >> 1) * 64, wc = (wave & 1) * 64;
    const int tx = lane & 15, quad = lane >> 4;
    const int txl = tx & 7;

    f32x4 acc[4][4] = {};

    for (int k0 = 0; k0 < Kd; k0 += 64) {
#pragma unroll
        for (int l = 0; l < 4; ++l) {
            const int lin = l * 2048 + tid * 8;
            const int r = lin >> 6;
            const int c = (((lin >> 3) & 7) ^ (r & 7)) * 8;  // XOR-swizzled src
            gload_lds16(A + (size_t)(row0 + r) * Kd + k0 + c, &As[lin]);
        }
#pragma unroll
        for (int l = 0; l < 4; ++l) {
            const int lin = l * 2048 + tid * 8;
            const int r = lin >> 6;
            const int c = (((lin >> 3) & 7) ^ (r & 7)) * 8;
            gload_lds16(Bm + (size_t)(col0 + r) * Kd + k0 + c, &Bs[lin]);
        }
        __syncthreads();
#pragma unroll
        for (int ks = 0; ks < 2; ++ks) {
            bf16x8 af[4], bfr[4];
            const int gsw = ((ks * 4 + quad) ^ txl) * 8;
#pragma unroll
            for (int i = 0; i < 4; ++i)
                af[i] = *(const bf16x8*)&As[(wr + i * 16 + tx) * 64 + gsw];
#pragma unroll
            for (int j = 0; j < 4; ++j)
                bfr[j] = *(const bf16x8*)&Bs[(wc + j * 16 + tx) * 64 + gsw];
#pragma unroll
            for (int i = 0; i < 4; ++i)
#pragma unroll
                for (int j = 0; j < 4; ++j)
                    acc[i][j] = __builtin_amdgcn_mfma_f32_16x16x32_bf16(
                        af[i], bfr[j], acc[i][j], 0, 0, 0);
        }
        __syncthreads();
    }

    // C/D layout (m89): col = lane&15, row = (lane>>4)*4 + reg
    if (EPI == EPI_LOSS) {
        float* loss = (float*)Cout;
        const float inv_n = 1.0f / (float)N;
#pragma unroll
        for (int i = 0; i < 4; ++i) {
#pragma unroll
            for (int r = 0; r < 4; ++r) {
                const int row = row0 + wr + i * 16 + quad * 4 + r;
                const float D = P_NULL * __expf(bias[row]) + Saux[row];
                const float invD = 1.0f / D;
                float s = 0.f;
#pragma unroll
                for (int j = 0; j < 4; ++j) {
                    const int col = col0 + wc + j * 16 + tx;
                    const float d = acc[i][j][r] * invD - X[(size_t)row * N + col];
                    s = fmaf(d, d, s);
                }
                s += __shfl_xor(s, 1, 64);
                s += __shfl_xor(s, 2, 64);
                s += __shfl_xor(s, 4, 64);
                s += __shfl_xor(s, 8, 64);
                if (tx == 0) atomicAdd(&loss[row], s * inv_n);
            }
        }
    } else {
        // ---- exp epilogue through LDS tile (whole smem, XOR-16 groups) ----
        if (EPI == EPI_WZ) {
            // stage e tile (coalesced; group permutation on global side)
#pragma unroll
            for (int l = 0; l < 8; ++l) {
                const int lin = l * 2048 + tid * 8;
                const int r = lin >> 7;
                const int g = (lin >> 3) & 15;
                const int c = (g ^ (r & 15)) << 3;
                gload_lds16(Paux + (size_t)(row0 + r) * N + col0 + c, &smem[lin]);
            }
        }
        __syncthreads();  // staging visible / K-loop reads done before overwrite

        // compute w/u, write tile to LDS, row-sum atomics
#pragma unroll
        for (int i = 0; i < 4; ++i) {
            float srow[4] = {0.f, 0.f, 0.f, 0.f};
#pragma unroll
            for (int j = 0; j < 4; ++j) {
                const int pcol = wc + j * 16 + tx;
                const float cb = bias[col0 + pcol];
#pragma unroll
                for (int r = 0; r < 4; ++r) {
                    const int prow = wr + i * 16 + quad * 4 + r;
                    const int paddr = prow * 128 +
                        (((pcol >> 3) ^ (prow & 15)) << 3) + (pcol & 7);
                    float v = __expf(fmaf(acc[i][j][r], alpha, -cb));
                    if (EPI == EPI_WZ) v *= bf2f(smem[paddr]);
                    srow[r] += v;
                    smem[paddr] = f2bf(v);
                }
            }
#pragma unroll
            for (int r = 0; r < 4; ++r) {
                float s = srow[r];
                s += __shfl_xor(s, 1, 64);
                s += __shfl_xor(s, 2, 64);
                s += __shfl_xor(s, 4, 64);
                s += __shfl_xor(s, 8, 64);
                if (tx == 0)
                    atomicAdd(&Saux[row0 + wr + i * 16 + quad * 4 + r], s);
            }
        }

        if (EPI == EPI_U) {
            __syncthreads();
            // vectorized store, 8 x uint4 per thread
            u16* C = (u16*)Cout;
            const int rr = tid >> 1, hs = tid & 1;
#pragma unroll
            for (int u = 0; u < 8; ++u) {
                const int gl = hs * 8 + u;
                const int pg = gl ^ (rr & 15);
                *(uint4*)(C + (size_t)(row0 + rr) * N + col0 + gl * 8) =
                    *(const uint4*)&smem[rr * 128 + pg * 8];
            }
        }

        if (EPI == EPI_WZ) {
            // ---- PHASE-2: Zacc(128 x E) += w_tile(128 x 128k) @ Xb2 slice ----
            // B2 frags from global (L2-hot 1MB xb), 16B/lane, loaded once and
            // reused across 4 row-chunks. Wave owns e-cols [wave*64, +64).
            const int e0w = wave * 64;
            bf16x8 b2[4][4];
#pragma unroll
            for (int f = 0; f < 4; ++f)
#pragma unroll
                for (int kk = 0; kk < 4; ++kk)
                    b2[f][kk] = *(const bf16x8*)&Xb2[
                        (size_t)(e0w + f * 16 + tx) * N + col0 + kk * 32 + quad * 8];
            __syncthreads();  // w tile complete before reading
#pragma unroll
            for (int rc = 0; rc < 4; ++rc) {
                f32x4 acc2[2][4] = {};
#pragma unroll
                for (int kk = 0; kk < 4; ++kk) {
                    bf16x8 a2[2];
#pragma unroll
                    for (int mi = 0; mi < 2; ++mi) {
                        const int row = rc * 32 + mi * 16 + tx;
                        const int kx = kk * 32 + quad * 8;
                        a2[mi] = *(const bf16x8*)&smem[
                            row * 128 + (((kx >> 3) ^ (row & 15)) << 3)];
                    }
#pragma unroll
                    for (int mi = 0; mi < 2; ++mi)
#pragma unroll
                        for (int f = 0; f < 4; ++f)
                            acc2[mi][f] = __builtin_amdgcn_mfma_f32_16x16x32_bf16(
                                a2[mi], b2[f][kk], acc2[mi][f], 0, 0, 0);
                }
#pragma unroll
                for (int mi = 0; mi < 2; ++mi)
#pragma unroll
                    for (int f = 0; f < 4; ++f)
#pragma unroll
                        for (int r = 0; r < 4; ++r) {
                            const int grow = row0 + rc * 32 + mi * 16 + quad * 4 + r;
                            const int ge = e0w + f * 16 + tx;
                            atomicAdd(&Zacc[(size_t)grow * E + ge], acc2[mi][f][r]);
                        }
            }
        }
    }
}

// ---------------------------------------------------------------------------
// MFMA bf16 GEMM (64x128 tile) for the initial z0 = e @ xb^T / S_enc[row].
// ---------------------------------------------------------------------------
__global__ __launch_bounds__(256) void mfma_gemm64_kernel(
    const u16* __restrict__ A, const u16* __restrict__ Bm,
    u16* __restrict__ C, const float* __restrict__ Srow,
    int M, int N, int Kd) {
    __shared__ u16 As[64 * 64];
    __shared__ u16 Bs[128 * 64];
    const int tid = threadIdx.x;
    int btr, btc;
    swizzle_tiles(btr, btc);
    const int row0 = btr * 64, col0 = btc * 128;
    const int lane = tid & 63, wave = tid >> 6;
    const int wr = (wave >> 1) * 32, wc = (wave & 1) * 64;
    const int tx = lane & 15, quad = lane >> 4;
    const int txl = tx & 7;

    f32x4 acc[2][4] = {};

    for (int k0 = 0; k0 < Kd; k0 += 64) {
#pragma unroll
        for (int l = 0; l < 2; ++l) {
            const int lin = l * 2048 + tid * 8;
            const int r = lin >> 6;
            const int c = (((lin >> 3) & 7) ^ (r & 7)) * 8;
            gload_lds16(A + (size_t)(row0 + r) * Kd + k0 + c, &As[lin]);
        }
#pragma unroll
        for (int l = 0; l < 4; ++l) {
            const int lin = l * 2048 + tid * 8;
            const int r = lin >> 6;
            const int c = (((lin >> 3) & 7) ^ (r & 7)) * 8;
            gload_lds16(Bm + (size_t)(col0 + r) * Kd + k0 + c, &Bs[lin]);
        }
        __syncthreads();
#pragma unroll
        for (int ks = 0; ks < 2; ++ks) {
            bf16x8 af[2], bfr[4];
            const int gsw = ((ks * 4 + quad) ^ txl) * 8;
#pragma unroll
            for (int i = 0; i < 2; ++i)
                af[i] = *(const bf16x8*)&As[(wr + i * 16 + tx) * 64 + gsw];
#pragma unroll
            for (int j = 0; j < 4; ++j)
                bfr[j] = *(const bf16x8*)&Bs[(wc + j * 16 + tx) * 64 + gsw];
#pragma unroll
            for (int i = 0; i < 2; ++i)
#pragma unroll
                for (int j = 0; j < 4; ++j)
                    acc[i][j] = __builtin_amdgcn_mfma_f32_16x16x32_bf16(
                        af[i], bfr[j], acc[i][j], 0, 0, 0);
        }
        __syncthreads();
    }

#pragma unroll
    for (int i = 0; i < 2; ++i)
#pragma unroll
        for (int r = 0; r < 4; ++r) {
            const int row = row0 + wr + i * 16 + quad * 4 + r;
            const float sc = Srow ? (1.0f / Srow[row]) : 1.0f;
#pragma unroll
            for (int j = 0; j < 4; ++j) {
                const int col = col0 + wc + j * 16 + tx;
                C[(size_t)row * N + col] = f2bf(acc[i][j][r] * sc);
            }
        }
}

// ---------------------------------------------------------------------------
// zconvert: z_bf[row,:] = bf16(Zacc[row,:]/Sw[row]); x2z[row] = mean(z_bf^2);
// re-zeroes Zacc for the next step's atomics. One block (256=E thr) per row.
// ---------------------------------------------------------------------------
__global__ __launch_bounds__(256) void zconvert_kernel(
    float* __restrict__ Zacc, const float* __restrict__ Sw,
    u16* __restrict__ Zbf, float* __restrict__ x2z) {
    __shared__ float sm[4];
    const size_t base = (size_t)blockIdx.x * E + threadIdx.x;
    const float inv = 1.0f / Sw[blockIdx.x];
    const float v = Zacc[base] * inv;
    Zacc[base] = 0.f;
    const u16 h = f2bf(v);
    Zbf[base] = h;
    const float vb = bf2f(h);
    const float s = block_sum256(vb * vb, sm);
    if (threadIdx.x == 0) x2z[blockIdx.x] = s * (1.0f / (float)E);
}

// ---------------------------------------------------------------------------
extern "C" void kernel_launch(void* const* d_in, const int* in_sizes, int n_in,
                              void* d_out, int out_size, void* d_ws, size_t ws_size,
                              hipStream_t stream) {
    const float* images = (const float*)d_in[0];  // (B,G)
    const float* xa     = (const float*)d_in[1];  // (G,K)
    const float* xb     = (const float*)d_in[2];  // (E,K)
    float* out = (float*)d_out;                   // (B,)

    // workspace carve-up (u16 elements, all regions 16B-aligned)
    u16* img_bf = (u16*)d_ws;                      // B*G
    u16* xa_bf  = img_bf + (size_t)B * G;          // G*K
    u16* xaT_bf = xa_bf + (size_t)G * K;           // K*G
    u16* xb_bf  = xaT_bf + (size_t)K * G;          // E*K
    u16* xbT_bf = xb_bf + (size_t)E * K;           // K*E
    u16* e_bf   = xbT_bf + (size_t)K * E;          // B*K (unnormalized enc e)
    u16* w_bf   = e_bf + (size_t)B * K;            // B*K (decode u)
    u16* z_bf   = w_bf + (size_t)B * K;            // B*E
    float* zf32 = (float*)(z_bf + (size_t)B * E);  // B*E f32 (phase-2 acc)
    float* c2a  = zf32 + (size_t)B * E;            // K   --+ one memset
    float* c2b  = c2a + K;                         // K     |
    float* Svec = c2b + K;                         // 6*B --+ (S_enc, Sw0..3, S0)
    float* x2z  = Svec + 6 * B;                    // B (fully written)

    (void)hipMemsetAsync(d_out, 0, (size_t)B * sizeof(float), stream);
    (void)hipMemsetAsync(zf32, 0,
                         ((size_t)B * E + 2 * K + 6 * B) * sizeof(float), stream);

    // prep: bf16 copies + transposes + column mean-squares (one read each)
    f2bf_kernel<<<(B * G) / 2048, 256, 0, stream>>>(images, img_bf, B * G);
    prep_kernel<<<dim3(K / 32, G / 32), 256, 0, stream>>>(
        xa, xa_bf, xaT_bf, c2a, G, K, 1.0f / (float)G);
    prep_kernel<<<dim3(K / 32, E / 32), 256, 0, stream>>>(
        xb, xb_bf, xbT_bf, c2b, E, K, 1.0f / (float)E);

    // encode (no softmax needed): e = exp(images@xa*(2/G) - c2a), S_enc = row-sum
    float* S_enc = Svec;
    mfma_gemm_kernel<EPI_U><<<dim3(K / 128, B / 128), 256, 0, stream>>>(
        img_bf, xaT_bf, e_bf, c2a, nullptr, nullptr, S_enc, nullptr, nullptr,
        B, K, G, 2.0f / (float)G);

    // z0 = (e @ xb^T) / S_enc[row]   (== pik @ xb^T)
    mfma_gemm64_kernel<<<dim3(E / 128, B / 64), 256, 0, stream>>>(
        e_bf, xb_bf, z_bf, S_enc, B, E, K);

    for (int s = 0; s < N_STEP; ++s) {
        float* Sw = Svec + (size_t)(1 + s) * B;
        // fused: w = e*exp(z@xb*(2/E)-c2b) (LDS only); Sw = row-sum(w);
        //        zf32 += w @ xb^T  (phase-2, atomics)
        mfma_gemm_kernel<EPI_WZ><<<dim3(K / 128, B / 128), 256, 0, stream>>>(
            z_bf, xbT_bf, nullptr, c2b, nullptr, e_bf, Sw, zf32, xb_bf,
            B, K, E, 2.0f / (float)E);
        // z = bf16(zf32 / Sw) ; x2z = mean(z^2) ; zf32 -> 0
        zconvert_kernel<<<B, 256, 0, stream>>>(zf32, Sw, z_bf, x2z);
    }

    // decode: u = exp(z@xb*(2/E) - c2b) ; S0[row] = row-sum(u)
    float* S0 = Svec + (size_t)5 * B;
    mfma_gemm_kernel<EPI_U><<<dim3(K / 128, B / 128), 256, 0, stream>>>(
        z_bf, xbT_bf, w_bf, c2b, nullptr, nullptr, S0, nullptr, nullptr,
        B, K, E, 2.0f / (float)E);

    // loss: recon = (u @ xa^T)/D[row], D = P_NULL*e^{x2}+S0 ;
    // loss[b] = mean_g (recon - images)^2
    mfma_gemm_kernel<EPI_LOSS><<<dim3(G / 128, B / 128), 256, 0, stream>>>(
        w_bf, xa_bf, out, x2z, images, nullptr, S0, nullptr, nullptr,
        B, G, K, 1.0f);
}

// Round 11
// 483.448 us; speedup vs baseline: 1.6723x; 1.6723x over previous
//
#include <hip/hip_runtime.h>
#include <hip/hip_bf16.h>

// Problem constants (match reference)
constexpr int B = 8192;
constexpr int G = 1024;
constexpr int E = 256;
constexpr int K = 2048;
constexpr float P_NULL = 0.1f;
constexpr int N_STEP = 4;

typedef unsigned short u16;
typedef short bf16x8 __attribute__((ext_vector_type(8)));
typedef float f32x4 __attribute__((ext_vector_type(4)));

// ---------------------------------------------------------------------------
// bf16 <-> f32 (RNE)
// ---------------------------------------------------------------------------
__device__ inline u16 f2bf(float f) {
    union { float f; uint32_t u; } cv;
    cv.f = f;
    const uint32_t u = cv.u;
    return (u16)((u + 0x7fffu + ((u >> 16) & 1u)) >> 16);
}
__device__ inline float bf2f(u16 h) {
    union { uint32_t u; float f; } cv;
    cv.u = ((uint32_t)h) << 16;
    return cv.f;
}
__device__ inline uint4 pack8(const float* v) {
    uint4 u;
    u.x = (uint32_t)f2bf(v[0]) | ((uint32_t)f2bf(v[1]) << 16);
    u.y = (uint32_t)f2bf(v[2]) | ((uint32_t)f2bf(v[3]) << 16);
    u.z = (uint32_t)f2bf(v[4]) | ((uint32_t)f2bf(v[5]) << 16);
    u.w = (uint32_t)f2bf(v[6]) | ((uint32_t)f2bf(v[7]) << 16);
    return u;
}

// async global->LDS, 16B per lane (LDS dest is lane-linear; global src is
// per-lane and may be permuted -> XOR-swizzle is applied on the GLOBAL side)
typedef __attribute__((address_space(1))) const void* gaddr_t;
typedef __attribute__((address_space(3))) void* laddr_t;
__device__ inline void gload_lds16(const void* g, void* l) {
    __builtin_amdgcn_global_load_lds((gaddr_t)g, (laddr_t)l, 16, 0, 0);
}

// XCD-aware tile swizzle (requires gridDim.y % 8 == 0)
__device__ inline void swizzle_tiles(int& tr, int& tc) {
    const int cx = gridDim.x, cy = gridDim.y;
    const int id = blockIdx.y * cx + blockIdx.x;
    const int k = id & 7;
    const int q = id >> 3;
    tr = k * (cy >> 3) + q / cx;
    tc = q % cx;
}

// ---------------------------------------------------------------------------
// Reduction helpers (256-thread blocks, wave64)
// ---------------------------------------------------------------------------
__device__ inline float wave_sum(float v) {
#pragma unroll
    for (int off = 32; off > 0; off >>= 1) v += __shfl_down(v, off, 64);
    return v;
}
__device__ inline float block_sum256(float v, float* sm) {
    v = wave_sum(v);
    const int w = threadIdx.x >> 6;
    if ((threadIdx.x & 63) == 0) sm[w] = v;
    __syncthreads();
    const float r = sm[0] + sm[1] + sm[2] + sm[3];
    __syncthreads();
    return r;
}

// ---------------------------------------------------------------------------
// f32 -> bf16 flat convert, 8 elems/thread
// ---------------------------------------------------------------------------
__global__ __launch_bounds__(256) void f2bf_kernel(
    const float* __restrict__ in, u16* __restrict__ out, int n) {
    const int i = (blockIdx.x * 256 + threadIdx.x) * 8;
    if (i + 7 >= n) {
        for (int j = i; j < n; ++j) out[j] = f2bf(in[j]);
        return;
    }
    const float4 a = *(const float4*)(in + i);
    const float4 b = *(const float4*)(in + i + 4);
    float v[8] = {a.x, a.y, a.z, a.w, b.x, b.y, b.z, b.w};
    *(uint4*)(out + i) = pack8(v);
}

// ---------------------------------------------------------------------------
// Fused prep: f32 (R,C) -> bf16 (R,C) copy + bf16 (C,R) transpose +
// csq[c] += (1/R) sum_r v^2.  grid (C/32, R/32), block 256.
// ---------------------------------------------------------------------------
__global__ __launch_bounds__(256) void prep_kernel(
    const float* __restrict__ in, u16* __restrict__ outN,
    u16* __restrict__ outT, float* __restrict__ csq, int R, int C,
    float inv_R) {
    __shared__ float tile[32][33];
    __shared__ float sred[8][32];
    const int bx = blockIdx.x * 32, by = blockIdx.y * 32;
    const int x = threadIdx.x & 31, y0 = threadIdx.x >> 5;
    float s = 0.f;
#pragma unroll
    for (int yy = 0; yy < 32; yy += 8) {
        const float v = in[(size_t)(by + y0 + yy) * C + bx + x];
        tile[y0 + yy][x] = v;
        outN[(size_t)(by + y0 + yy) * C + bx + x] = f2bf(v);
        s = fmaf(v, v, s);
    }
    sred[y0][x] = s;
    __syncthreads();
#pragma unroll
    for (int yy = 0; yy < 32; yy += 8)
        outT[(size_t)(bx + y0 + yy) * R + by + x] = f2bf(tile[x][y0 + yy]);
    if (y0 == 0) {
        float t = 0.f;
#pragma unroll
        for (int k2 = 0; k2 < 8; ++k2) t += sred[k2][x];
        atomicAdd(csq + bx + x, t * inv_R);
    }
}

// ---------------------------------------------------------------------------
// MFMA bf16 GEMM, 128x64 tile, BK=64, 256 thr = 4 waves (wave owns 32 rows x
// all 64 cols). Small tile -> 2048-block grid -> ~2 co-resident rounds/CU for
// request-concurrency (R10 analysis: pipeline was BW-limited at 1.4 TB/s by
// single-round grids). LDS XOR-swizzled on the GLOBAL source (verified R7,
// 0 conflicts). Epilogues:
//   EPI_U: u = exp(alpha*acc - bias[col]) -> bf16 C; Saux[row] += row-sum
//   EPI_W: w = e[row,col]*exp(alpha*acc - bias[col]) -> bf16 C;
//          Saux[row] += row-sum  (e unnormalized; 1/S_enc cancels in w/Sum w)
// ---------------------------------------------------------------------------
enum { EPI_U = 0, EPI_W = 1 };

template <int EPI>
__global__ __launch_bounds__(256) void mfma_n64_kernel(
    const u16* __restrict__ A, const u16* __restrict__ Bm,
    u16* __restrict__ C, const float* __restrict__ bias,
    const u16* __restrict__ Paux, float* __restrict__ Saux,
    int M, int N, int Kd, float alpha) {
    __shared__ u16 smem[12288];  // As 8192 (128x64) | Bs 4096 (64x64); 24 KB
    u16* As = smem;
    u16* Bs = smem + 8192;
    const int tid = threadIdx.x;
    int btr, btc;
    swizzle_tiles(btr, btc);
    const int row0 = btr * 128, col0 = btc * 64;
    const int lane = tid & 63, wave = tid >> 6;
    const int wr = wave * 32;
    const int tx = lane & 15, quad = lane >> 4;
    const int txl = tx & 7;

    f32x4 acc[2][4] = {};

    for (int k0 = 0; k0 < Kd; k0 += 64) {
#pragma unroll
        for (int l = 0; l < 4; ++l) {
            const int lin = l * 2048 + tid * 8;
            const int r = lin >> 6;
            const int c = (((lin >> 3) & 7) ^ (r & 7)) * 8;  // XOR-swizzled src
            gload_lds16(A + (size_t)(row0 + r) * Kd + k0 + c, &As[lin]);
        }
#pragma unroll
        for (int l = 0; l < 2; ++l) {
            const int lin = l * 2048 + tid * 8;
            const int r = lin >> 6;
            const int c = (((lin >> 3) & 7) ^ (r & 7)) * 8;
            gload_lds16(Bm + (size_t)(col0 + r) * Kd + k0 + c, &Bs[lin]);
        }
        __syncthreads();
#pragma unroll
        for (int ks = 0; ks < 2; ++ks) {
            bf16x8 af[2], bfr[4];
            const int gsw = ((ks * 4 + quad) ^ txl) * 8;
#pragma unroll
            for (int i = 0; i < 2; ++i)
                af[i] = *(const bf16x8*)&As[(wr + i * 16 + tx) * 64 + gsw];
#pragma unroll
            for (int j = 0; j < 4; ++j)
                bfr[j] = *(const bf16x8*)&Bs[(j * 16 + tx) * 64 + gsw];
#pragma unroll
            for (int i = 0; i < 2; ++i)
#pragma unroll
                for (int j = 0; j < 4; ++j)
                    acc[i][j] = __builtin_amdgcn_mfma_f32_16x16x32_bf16(
                        af[i], bfr[j], acc[i][j], 0, 0, 0);
        }
        __syncthreads();
    }

    // ---- epilogue through LDS tile (128x64 in As region, XOR-8 groups) ----
    if (EPI == EPI_W) {
        // stage e tile (coalesced; group permutation on global side)
#pragma unroll
        for (int l = 0; l < 4; ++l) {
            const int lin = l * 2048 + tid * 8;
            const int r = lin >> 6;
            const int g = (lin >> 3) & 7;
            const int c = (g ^ (r & 7)) << 3;
            gload_lds16(Paux + (size_t)(row0 + r) * N + col0 + c, &smem[lin]);
        }
    }
    __syncthreads();

    // compute w/u (C/D layout m89: col=lane&15, row=quad*4+reg), row sums
#pragma unroll
    for (int i = 0; i < 2; ++i) {
        float srow[4] = {0.f, 0.f, 0.f, 0.f};
#pragma unroll
        for (int j = 0; j < 4; ++j) {
            const int pcol = j * 16 + tx;
            const float cb = bias[col0 + pcol];
#pragma unroll
            for (int r = 0; r < 4; ++r) {
                const int prow = wr + i * 16 + quad * 4 + r;
                const int paddr = prow * 64 +
                    (((pcol >> 3) ^ (prow & 7)) << 3) + (pcol & 7);
                float v = __expf(fmaf(acc[i][j][r], alpha, -cb));
                if (EPI == EPI_W) v *= bf2f(smem[paddr]);
                srow[r] += v;
                smem[paddr] = f2bf(v);
            }
        }
#pragma unroll
        for (int r = 0; r < 4; ++r) {
            float s = srow[r];
            s += __shfl_xor(s, 1, 64);
            s += __shfl_xor(s, 2, 64);
            s += __shfl_xor(s, 4, 64);
            s += __shfl_xor(s, 8, 64);
            if (tx == 0)
                atomicAdd(&Saux[row0 + wr + i * 16 + quad * 4 + r], s);
        }
    }
    __syncthreads();

    // vectorized store: 4 x uint4 per thread
    const int rr = tid >> 1, hs = tid & 1;
#pragma unroll
    for (int u = 0; u < 4; ++u) {
        const int gl = hs * 4 + u;
        const int pg = gl ^ (rr & 7);
        *(uint4*)(C + (size_t)(row0 + rr) * N + col0 + gl * 8) =
            *(const uint4*)&smem[rr * 64 + pg * 8];
    }
}

// ---------------------------------------------------------------------------
// MFMA bf16 GEMM, 64x64 tile, for the (B,E) z-GEMMs: grid (E/64, B/64) = 512
// blocks (2x the old 64x128 grid). z = (A @ Bm^T) / Srow[row].
// ---------------------------------------------------------------------------
__global__ __launch_bounds__(256) void mfma_z64_kernel(
    const u16* __restrict__ A, const u16* __restrict__ Bm,
    u16* __restrict__ C, const float* __restrict__ Srow,
    int M, int N, int Kd) {
    __shared__ u16 As[64 * 64];
    __shared__ u16 Bs[64 * 64];
    const int tid = threadIdx.x;
    int btr, btc;
    swizzle_tiles(btr, btc);
    const int row0 = btr * 64, col0 = btc * 64;
    const int lane = tid & 63, wave = tid >> 6;
    const int wr = (wave >> 1) * 32, wc = (wave & 1) * 32;
    const int tx = lane & 15, quad = lane >> 4;
    const int txl = tx & 7;

    f32x4 acc[2][2] = {};

    for (int k0 = 0; k0 < Kd; k0 += 64) {
#pragma unroll
        for (int l = 0; l < 2; ++l) {
            const int lin = l * 2048 + tid * 8;
            const int r = lin >> 6;
            const int c = (((lin >> 3) & 7) ^ (r & 7)) * 8;
            gload_lds16(A + (size_t)(row0 + r) * Kd + k0 + c, &As[lin]);
        }
#pragma unroll
        for (int l = 0; l < 2; ++l) {
            const int lin = l * 2048 + tid * 8;
            const int r = lin >> 6;
            const int c = (((lin >> 3) & 7) ^ (r & 7)) * 8;
            gload_lds16(Bm + (size_t)(col0 + r) * Kd + k0 + c, &Bs[lin]);
        }
        __syncthreads();
#pragma unroll
        for (int ks = 0; ks < 2; ++ks) {
            bf16x8 af[2], bfr[2];
            const int gsw = ((ks * 4 + quad) ^ txl) * 8;
#pragma unroll
            for (int i = 0; i < 2; ++i)
                af[i] = *(const bf16x8*)&As[(wr + i * 16 + tx) * 64 + gsw];
#pragma unroll
            for (int j = 0; j < 2; ++j)
                bfr[j] = *(const bf16x8*)&Bs[(wc + j * 16 + tx) * 64 + gsw];
#pragma unroll
            for (int i = 0; i < 2; ++i)
#pragma unroll
                for (int j = 0; j < 2; ++j)
                    acc[i][j] = __builtin_amdgcn_mfma_f32_16x16x32_bf16(
                        af[i], bfr[j], acc[i][j], 0, 0, 0);
        }
        __syncthreads();
    }

#pragma unroll
    for (int i = 0; i < 2; ++i)
#pragma unroll
        for (int r = 0; r < 4; ++r) {
            const int row = row0 + wr + i * 16 + quad * 4 + r;
            const float sc = Srow ? (1.0f / Srow[row]) : 1.0f;
#pragma unroll
            for (int j = 0; j < 2; ++j) {
                const int col = col0 + wc + j * 16 + tx;
                C[(size_t)row * N + col] = f2bf(acc[i][j][r] * sc);
            }
        }
}

// ---------------------------------------------------------------------------
// MFMA bf16 GEMM (128x128 tile) with fused MSE-loss epilogue (kept from R9):
// D = P_NULL*exp(x2[row]) + S0[row];
// loss[row] += (1/N)*sum_col (acc/D - X[row,col])^2
// ---------------------------------------------------------------------------
__global__ __launch_bounds__(256) void mfma_loss_kernel(
    const u16* __restrict__ A, const u16* __restrict__ Bm,
    float* __restrict__ loss, const float* __restrict__ x2,
    const float* __restrict__ X, const float* __restrict__ S0,
    int M, int N, int Kd) {
    __shared__ u16 As[128 * 64];
    __shared__ u16 Bs[128 * 64];
    const int tid = threadIdx.x;
    int btr, btc;
    swizzle_tiles(btr, btc);
    const int row0 = btr * 128, col0 = btc * 128;
    const int lane = tid & 63, wave = tid >> 6;
    const int wr = (wave >> 1) * 64, wc = (wave & 1) * 64;
    const int tx = lane & 15, quad = lane >> 4;
    const int txl = tx & 7;

    f32x4 acc[4][4] = {};

    for (int k0 = 0; k0 < Kd; k0 += 64) {
#pragma unroll
        for (int l = 0; l < 4; ++l) {
            const int lin = l * 2048 + tid * 8;
            const int r = lin >> 6;
            const int c = (((lin >> 3) & 7) ^ (r & 7)) * 8;
            gload_lds16(A + (size_t)(row0 + r) * Kd + k0 + c, &As[lin]);
        }
#pragma unroll
        for (int l = 0; l < 4; ++l) {
            const int lin = l * 2048 + tid * 8;
            const int r = lin >> 6;
            const int c = (((lin >> 3) & 7) ^ (r & 7)) * 8;
            gload_lds16(Bm + (size_t)(col0 + r) * Kd + k0 + c, &Bs[lin]);
        }
        __syncthreads();
#pragma unroll
        for (int ks = 0; ks < 2; ++ks) {
            bf16x8 af[4], bfr[4];
            const int gsw = ((ks * 4 + quad) ^ txl) * 8;
#pragma unroll
            for (int i = 0; i < 4; ++i)
                af[i] = *(const bf16x8*)&As[(wr + i * 16 + tx) * 64 + gsw];
#pragma unroll
            for (int j = 0; j < 4; ++j)
                bfr[j] = *(const bf16x8*)&Bs[(wc + j * 16 + tx) * 64 + gsw];
#pragma unroll
            for (int i = 0; i < 4; ++i)
#pragma unroll
                for (int j = 0; j < 4; ++j)
                    acc[i][j] = __builtin_amdgcn_mfma_f32_16x16x32_bf16(
                        af[i], bfr[j], acc[i][j], 0, 0, 0);
        }
        __syncthreads();
    }

    const float inv_n = 1.0f / (float)N;
#pragma unroll
    for (int i = 0; i < 4; ++i) {
#pragma unroll
        for (int r = 0; r < 4; ++r) {
            const int row = row0 + wr + i * 16 + quad * 4 + r;
            const float D = P_NULL * __expf(x2[row]) + S0[row];
            const float invD = 1.0f / D;
            float s = 0.f;
#pragma unroll
            for (int j = 0; j < 4; ++j) {
                const int col = col0 + wc + j * 16 + tx;
                const float d = acc[i][j][r] * invD - X[(size_t)row * N + col];
                s = fmaf(d, d, s);
            }
            s += __shfl_xor(s, 1, 64);
            s += __shfl_xor(s, 2, 64);
            s += __shfl_xor(s, 4, 64);
            s += __shfl_xor(s, 8, 64);
            if (tx == 0) atomicAdd(&loss[row], s * inv_n);
        }
    }
}

// ---------------------------------------------------------------------------
// Row mean of squares of Z (B,E) bf16: x2[row] = mean(Z[row,:]^2)
// ---------------------------------------------------------------------------
__global__ __launch_bounds__(256) void rowmeansq_bf_kernel(
    const u16* __restrict__ Z, float* __restrict__ out) {
    __shared__ float sm[4];
    const float v = bf2f(Z[(size_t)blockIdx.x * E + threadIdx.x]);
    const float s = block_sum256(v * v, sm);
    if (threadIdx.x == 0) out[blockIdx.x] = s * (1.0f / (float)E);
}

// ---------------------------------------------------------------------------
extern "C" void kernel_launch(void* const* d_in, const int* in_sizes, int n_in,
                              void* d_out, int out_size, void* d_ws, size_t ws_size,
                              hipStream_t stream) {
    const float* images = (const float*)d_in[0];  // (B,G)
    const float* xa     = (const float*)d_in[1];  // (G,K)
    const float* xb     = (const float*)d_in[2];  // (E,K)
    float* out = (float*)d_out;                   // (B,)

    // workspace carve-up (u16 elements, all regions 16B-aligned)
    u16* img_bf = (u16*)d_ws;                      // B*G
    u16* xa_bf  = img_bf + (size_t)B * G;          // G*K
    u16* xaT_bf = xa_bf + (size_t)G * K;           // K*G
    u16* xb_bf  = xaT_bf + (size_t)K * G;          // E*K
    u16* xbT_bf = xb_bf + (size_t)E * K;           // K*E
    u16* e_bf   = xbT_bf + (size_t)K * E;          // B*K (unnormalized enc e)
    u16* wu_bf  = e_bf + (size_t)B * K;            // B*K (loop w / decode u)
    u16* z_bf   = wu_bf + (size_t)B * K;           // B*E
    float* c2a  = (float*)(z_bf + (size_t)B * E);  // K   --+ one memset
    float* c2b  = c2a + K;                         // K     |
    float* Svec = c2b + K;                         // 6*B --+ (S_enc,Sw0..3,S0)
    float* x2z  = Svec + 6 * B;                    // B (fully written)

    (void)hipMemsetAsync(d_out, 0, (size_t)B * sizeof(float), stream);
    (void)hipMemsetAsync(c2a, 0, (size_t)(2 * K + 6 * B) * sizeof(float), stream);

    // prep: bf16 copies + transposes + column mean-squares (one read each)
    f2bf_kernel<<<(B * G) / 2048, 256, 0, stream>>>(images, img_bf, B * G);
    prep_kernel<<<dim3(K / 32, G / 32), 256, 0, stream>>>(
        xa, xa_bf, xaT_bf, c2a, G, K, 1.0f / (float)G);
    prep_kernel<<<dim3(K / 32, E / 32), 256, 0, stream>>>(
        xb, xb_bf, xbT_bf, c2b, E, K, 1.0f / (float)E);

    // encode (softmax eliminated): e = exp(images@xa*(2/G) - c2a), S_enc=rowsum
    float* S_enc = Svec;
    mfma_n64_kernel<EPI_U><<<dim3(K / 64, B / 128), 256, 0, stream>>>(
        img_bf, xaT_bf, e_bf, c2a, nullptr, S_enc, B, K, G, 2.0f / (float)G);

    // z0 = (e @ xb^T) / S_enc[row]   (== pik @ xb^T)
    mfma_z64_kernel<<<dim3(E / 64, B / 64), 256, 0, stream>>>(
        e_bf, xb_bf, z_bf, S_enc, B, E, K);

    for (int s = 0; s < N_STEP; ++s) {
        float* Sw = Svec + (size_t)(1 + s) * B;
        // w = e*exp(z@xb*(2/E) - c2b) ; Sw[row] = sum_k w  (atomic)
        mfma_n64_kernel<EPI_W><<<dim3(K / 64, B / 128), 256, 0, stream>>>(
            z_bf, xbT_bf, wu_bf, c2b, e_bf, Sw, B, K, E, 2.0f / (float)E);
        // z = (w @ xb^T) / Sw[row]
        mfma_z64_kernel<<<dim3(E / 64, B / 64), 256, 0, stream>>>(
            wu_bf, xb_bf, z_bf, Sw, B, E, K);
    }

    // decode: x2 = mean(z^2) ; u = exp(z@xb*(2/E) - c2b) ; S0 = rowsum(u)
    float* S0 = Svec + (size_t)5 * B;
    rowmeansq_bf_kernel<<<B, 256, 0, stream>>>(z_bf, x2z);
    mfma_n64_kernel<EPI_U><<<dim3(K / 64, B / 128), 256, 0, stream>>>(
        z_bf, xbT_bf, wu_bf, c2b, nullptr, S0, B, K, E, 2.0f / (float)E);

    // loss: recon = (u @ xa^T)/D[row], D = P_NULL*e^{x2}+S0 ;
    // loss[b] = mean_g (recon - images)^2
    mfma_loss_kernel<<<dim3(G / 128, B / 128), 256, 0, stream>>>(
        wu_bf, xa_bf, out, x2z, images, S0, B, G, K);
}

// Round 13
// 482.947 us; speedup vs baseline: 1.6740x; 1.0010x over previous
//
#include <hip/hip_runtime.h>
#include <hip/hip_bf16.h>

// Problem constants (match reference)
constexpr int B = 8192;
constexpr int G = 1024;
constexpr int E = 256;
constexpr int K = 2048;
constexpr float P_NULL = 0.1f;
constexpr int N_STEP = 4;

typedef unsigned short u16;
typedef short bf16x8 __attribute__((ext_vector_type(8)));
typedef float f32x4 __attribute__((ext_vector_type(4)));

// ---------------------------------------------------------------------------
// bf16 <-> f32 (RNE)
// ---------------------------------------------------------------------------
__device__ inline u16 f2bf(float f) {
    union { float f; uint32_t u; } cv;
    cv.f = f;
    const uint32_t u = cv.u;
    return (u16)((u + 0x7fffu + ((u >> 16) & 1u)) >> 16);
}
__device__ inline float bf2f(u16 h) {
    union { uint32_t u; float f; } cv;
    cv.u = ((uint32_t)h) << 16;
    return cv.f;
}
__device__ inline uint4 pack8(const float* v) {
    uint4 u;
    u.x = (uint32_t)f2bf(v[0]) | ((uint32_t)f2bf(v[1]) << 16);
    u.y = (uint32_t)f2bf(v[2]) | ((uint32_t)f2bf(v[3]) << 16);
    u.z = (uint32_t)f2bf(v[4]) | ((uint32_t)f2bf(v[5]) << 16);
    u.w = (uint32_t)f2bf(v[6]) | ((uint32_t)f2bf(v[7]) << 16);
    return u;
}

// async global->LDS, 16B per lane (LDS dest is lane-linear; global src is
// per-lane and may be permuted -> XOR-swizzle is applied on the GLOBAL side)
typedef __attribute__((address_space(1))) const void* gaddr_t;
typedef __attribute__((address_space(3))) void* laddr_t;
__device__ inline void gload_lds16(const void* g, void* l) {
    __builtin_amdgcn_global_load_lds((gaddr_t)g, (laddr_t)l, 16, 0, 0);
}

// XCD-aware tile swizzle (requires gridDim.y % 8 == 0)
__device__ inline void swizzle_tiles(int& tr, int& tc) {
    const int cx = gridDim.x, cy = gridDim.y;
    const int id = blockIdx.y * cx + blockIdx.x;
    const int k = id & 7;
    const int q = id >> 3;
    tr = k * (cy >> 3) + q / cx;
    tc = q % cx;
}

// ---------------------------------------------------------------------------
// Reduction helpers (256-thread blocks, wave64)
// ---------------------------------------------------------------------------
__device__ inline float wave_sum(float v) {
#pragma unroll
    for (int off = 32; off > 0; off >>= 1) v += __shfl_down(v, off, 64);
    return v;
}
__device__ inline float block_sum256(float v, float* sm) {
    v = wave_sum(v);
    const int w = threadIdx.x >> 6;
    if ((threadIdx.x & 63) == 0) sm[w] = v;
    __syncthreads();
    const float r = sm[0] + sm[1] + sm[2] + sm[3];
    __syncthreads();
    return r;
}

// ---------------------------------------------------------------------------
// f32 -> bf16 flat convert, 8 elems/thread
// ---------------------------------------------------------------------------
__global__ __launch_bounds__(256) void f2bf_kernel(
    const float* __restrict__ in, u16* __restrict__ out, int n) {
    const int i = (blockIdx.x * 256 + threadIdx.x) * 8;
    if (i + 7 >= n) {
        for (int j = i; j < n; ++j) out[j] = f2bf(in[j]);
        return;
    }
    const float4 a = *(const float4*)(in + i);
    const float4 b = *(const float4*)(in + i + 4);
    float v[8] = {a.x, a.y, a.z, a.w, b.x, b.y, b.z, b.w};
    *(uint4*)(out + i) = pack8(v);
}

// ---------------------------------------------------------------------------
// Fused prep: f32 (R,C) -> bf16 (R,C) copy + bf16 (C,R) transpose +
// csq[c] += (1/R) sum_r v^2.  grid (C/32, R/32), block 256.
// ---------------------------------------------------------------------------
__global__ __launch_bounds__(256) void prep_kernel(
    const float* __restrict__ in, u16* __restrict__ outN,
    u16* __restrict__ outT, float* __restrict__ csq, int R, int C,
    float inv_R) {
    __shared__ float tile[32][33];
    __shared__ float sred[8][32];
    const int bx = blockIdx.x * 32, by = blockIdx.y * 32;
    const int x = threadIdx.x & 31, y0 = threadIdx.x >> 5;
    float s = 0.f;
#pragma unroll
    for (int yy = 0; yy < 32; yy += 8) {
        const float v = in[(size_t)(by + y0 + yy) * C + bx + x];
        tile[y0 + yy][x] = v;
        outN[(size_t)(by + y0 + yy) * C + bx + x] = f2bf(v);
        s = fmaf(v, v, s);
    }
    sred[y0][x] = s;
    __syncthreads();
#pragma unroll
    for (int yy = 0; yy < 32; yy += 8)
        outT[(size_t)(bx + y0 + yy) * R + by + x] = f2bf(tile[x][y0 + yy]);
    if (y0 == 0) {
        float t = 0.f;
#pragma unroll
        for (int k2 = 0; k2 < 8; ++k2) t += sred[k2][x];
        atomicAdd(csq + bx + x, t * inv_R);
    }
}

// ---------------------------------------------------------------------------
// MFMA bf16 GEMM, 128x64 tile (R11, kept for encode/decode):
//   EPI_U: u = exp(alpha*acc - bias[col]) -> bf16 C; Saux[row] += row-sum
//   EPI_W: kept for reference (unused in this round)
// ---------------------------------------------------------------------------
enum { EPI_U = 0, EPI_W = 1 };

template <int EPI>
__global__ __launch_bounds__(256) void mfma_n64_kernel(
    const u16* __restrict__ A, const u16* __restrict__ Bm,
    u16* __restrict__ C, const float* __restrict__ bias,
    const u16* __restrict__ Paux, float* __restrict__ Saux,
    int M, int N, int Kd, float alpha) {
    __shared__ u16 smem[12288];  // As 8192 (128x64) | Bs 4096 (64x64)
    u16* As = smem;
    u16* Bs = smem + 8192;
    const int tid = threadIdx.x;
    int btr, btc;
    swizzle_tiles(btr, btc);
    const int row0 = btr * 128, col0 = btc * 64;
    const int lane = tid & 63, wave = tid >> 6;
    const int wr = wave * 32;
    const int tx = lane & 15, quad = lane >> 4;
    const int txl = tx & 7;

    f32x4 acc[2][4] = {};

    for (int k0 = 0; k0 < Kd; k0 += 64) {
#pragma unroll
        for (int l = 0; l < 4; ++l) {
            const int lin = l * 2048 + tid * 8;
            const int r = lin >> 6;
            const int c = (((lin >> 3) & 7) ^ (r & 7)) * 8;  // XOR-swizzled src
            gload_lds16(A + (size_t)(row0 + r) * Kd + k0 + c, &As[lin]);
        }
#pragma unroll
        for (int l = 0; l < 2; ++l) {
            const int lin = l * 2048 + tid * 8;
            const int r = lin >> 6;
            const int c = (((lin >> 3) & 7) ^ (r & 7)) * 8;
            gload_lds16(Bm + (size_t)(col0 + r) * Kd + k0 + c, &Bs[lin]);
        }
        __syncthreads();
#pragma unroll
        for (int ks = 0; ks < 2; ++ks) {
            bf16x8 af[2], bfr[4];
            const int gsw = ((ks * 4 + quad) ^ txl) * 8;
#pragma unroll
            for (int i = 0; i < 2; ++i)
                af[i] = *(const bf16x8*)&As[(wr + i * 16 + tx) * 64 + gsw];
#pragma unroll
            for (int j = 0; j < 4; ++j)
                bfr[j] = *(const bf16x8*)&Bs[(j * 16 + tx) * 64 + gsw];
#pragma unroll
            for (int i = 0; i < 2; ++i)
#pragma unroll
                for (int j = 0; j < 4; ++j)
                    acc[i][j] = __builtin_amdgcn_mfma_f32_16x16x32_bf16(
                        af[i], bfr[j], acc[i][j], 0, 0, 0);
        }
        __syncthreads();
    }

    if (EPI == EPI_W) {
#pragma unroll
        for (int l = 0; l < 4; ++l) {
            const int lin = l * 2048 + tid * 8;
            const int r = lin >> 6;
            const int g = (lin >> 3) & 7;
            const int c = (g ^ (r & 7)) << 3;
            gload_lds16(Paux + (size_t)(row0 + r) * N + col0 + c, &smem[lin]);
        }
    }
    __syncthreads();

#pragma unroll
    for (int i = 0; i < 2; ++i) {
        float srow[4] = {0.f, 0.f, 0.f, 0.f};
#pragma unroll
        for (int j = 0; j < 4; ++j) {
            const int pcol = j * 16 + tx;
            const float cb = bias[col0 + pcol];
#pragma unroll
            for (int r = 0; r < 4; ++r) {
                const int prow = wr + i * 16 + quad * 4 + r;
                const int paddr = prow * 64 +
                    (((pcol >> 3) ^ (prow & 7)) << 3) + (pcol & 7);
                float v = __expf(fmaf(acc[i][j][r], alpha, -cb));
                if (EPI == EPI_W) v *= bf2f(smem[paddr]);
                srow[r] += v;
                smem[paddr] = f2bf(v);
            }
        }
#pragma unroll
        for (int r = 0; r < 4; ++r) {
            float s = srow[r];
            s += __shfl_xor(s, 1, 64);
            s += __shfl_xor(s, 2, 64);
            s += __shfl_xor(s, 4, 64);
            s += __shfl_xor(s, 8, 64);
            if (tx == 0)
                atomicAdd(&Saux[row0 + wr + i * 16 + quad * 4 + r], s);
        }
    }
    __syncthreads();

    const int rr = tid >> 1, hs = tid & 1;
#pragma unroll
    for (int u = 0; u < 4; ++u) {
        const int gl = hs * 4 + u;
        const int pg = gl ^ (rr & 7);
        *(uint4*)(C + (size_t)(row0 + rr) * N + col0 + gl * 8) =
            *(const uint4*)&smem[rr * 64 + pg * 8];
    }
}

// ---------------------------------------------------------------------------
// MFMA bf16 GEMM, 64x64 tile, for z0 = (e @ xb^T) / S_enc[row].
// ---------------------------------------------------------------------------
__global__ __launch_bounds__(256) void mfma_z64_kernel(
    const u16* __restrict__ A, const u16* __restrict__ Bm,
    u16* __restrict__ C, const float* __restrict__ Srow,
    int M, int N, int Kd) {
    __shared__ u16 As[64 * 64];
    __shared__ u16 Bs[64 * 64];
    const int tid = threadIdx.x;
    int btr, btc;
    swizzle_tiles(btr, btc);
    const int row0 = btr * 64, col0 = btc * 64;
    const int lane = tid & 63, wave = tid >> 6;
    const int wr = (wave >> 1) * 32, wc = (wave & 1) * 32;
    const int tx = lane & 15, quad = lane >> 4;
    const int txl = tx & 7;

    f32x4 acc[2][2] = {};

    for (int k0 = 0; k0 < Kd; k0 += 64) {
#pragma unroll
        for (int l = 0; l < 2; ++l) {
            const int lin = l * 2048 + tid * 8;
            const int r = lin >> 6;
            const int c = (((lin >> 3) & 7) ^ (r & 7)) * 8;
            gload_lds16(A + (size_t)(row0 + r) * Kd + k0 + c, &As[lin]);
        }
#pragma unroll
        for (int l = 0; l < 2; ++l) {
            const int lin = l * 2048 + tid * 8;
            const int r = lin >> 6;
            const int c = (((lin >> 3) & 7) ^ (r & 7)) * 8;
            gload_lds16(Bm + (size_t)(col0 + r) * Kd + k0 + c, &Bs[lin]);
        }
        __syncthreads();
#pragma unroll
        for (int ks = 0; ks < 2; ++ks) {
            bf16x8 af[2], bfr[2];
            const int gsw = ((ks * 4 + quad) ^ txl) * 8;
#pragma unroll
            for (int i = 0; i < 2; ++i)
                af[i] = *(const bf16x8*)&As[(wr + i * 16 + tx) * 64 + gsw];
#pragma unroll
            for (int j = 0; j < 2; ++j)
                bfr[j] = *(const bf16x8*)&Bs[(wc + j * 16 + tx) * 64 + gsw];
#pragma unroll
            for (int i = 0; i < 2; ++i)
#pragma unroll
                for (int j = 0; j < 2; ++j)
                    acc[i][j] = __builtin_amdgcn_mfma_f32_16x16x32_bf16(
                        af[i], bfr[j], acc[i][j], 0, 0, 0);
        }
        __syncthreads();
    }

#pragma unroll
    for (int i = 0; i < 2; ++i)
#pragma unroll
        for (int r = 0; r < 4; ++r) {
            const int row = row0 + wr + i * 16 + quad * 4 + r;
            const float sc = Srow ? (1.0f / Srow[row]) : 1.0f;
#pragma unroll
            for (int j = 0; j < 2; ++j) {
                const int col = col0 + wc + j * 16 + tx;
                C[(size_t)row * N + col] = f2bf(acc[i][j][r] * sc);
            }
        }
}

// ---------------------------------------------------------------------------
// FUSED loop-step kernel (row-split, no atomics; math verified in R10):
// per 32-row band:  t = (2/E)(z @ xbT) - c2b ; w = e*exp(t) (LDS only);
// Sw = row-sum(w) ; z <- (w @ xb^T)/Sw  (in place).
// grid = B/32 = 256 blocks, 256 thr = 4 waves. Each wave: all 32 rows (M=32),
// 16 of 64 chunk k-cols (t-part), 64 of 256 e-cols (z-part).
// All LDS tiles use the R7-verified 64-col XOR-8 layout (swizzle on global
// source for global_load_lds stages; conflict-free b128 frag reads).
// w NEVER touches HBM. HBM per step: e read 32MB + z i/o 8MB.
// ---------------------------------------------------------------------------
__global__ __launch_bounds__(256, 1) void step_kernel(
    u16* __restrict__ Z,            // (B,E) in/out
    const u16* __restrict__ XbT,    // (K,E)
    const u16* __restrict__ Xb,     // (E,K)
    const u16* __restrict__ Ebf,    // (B,K) unnormalized encode weights
    const float* __restrict__ c2b) {
    __shared__ u16 xbts[64 * 256];  // 32KB: 4 subtiles [q][64k][64e]
    __shared__ u16 xbs[256 * 64];   // 32KB: [256e][64k]
    __shared__ u16 ws[32 * 64];     // 4KB: w transit (C-layout -> A-frags)
    __shared__ u16 es[32 * 64];     // 4KB: e chunk
    __shared__ float c2s[K];        // 8KB
    __shared__ float redS[4][32];   // Sw partials per wave
    const int tid = threadIdx.x;
    const int lane = tid & 63, wave = tid >> 6;
    const int tx = lane & 15, quad = lane >> 4;
    const int row0 = blockIdx.x * 32;
    const float ascale = 2.0f / (float)E;

    // ---- one-time staging: c2b + z band (subtile-64 layout inside xbts) ----
    gload_lds16(c2b + tid * 4, &c2s[tid * 4]);
    gload_lds16(c2b + 1024 + tid * 4, &c2s[1024 + tid * 4]);
#pragma unroll
    for (int l = 0; l < 4; ++l) {
        const int lin = l * 2048 + tid * 8;
        const int q = lin >> 11, r = (lin >> 6) & 31, g = (lin >> 3) & 7;
        gload_lds16(Z + (size_t)(row0 + r) * E + q * 64 + ((g ^ (r & 7)) << 3),
                    &xbts[lin]);
    }
    __syncthreads();

    // z A-frags to registers: af[i][s], i = row-half, s covers E=256
    bf16x8 af[2][8];
#pragma unroll
    for (int i = 0; i < 2; ++i) {
        const int row = i * 16 + tx;
#pragma unroll
        for (int s = 0; s < 8; ++s) {
            const int g = ((s & 1) * 4 + quad) ^ (row & 7);
            af[i][s] = *(const bf16x8*)&xbts[(s >> 1) * 2048 + row * 64 + (g << 3)];
        }
    }
    __syncthreads();

    f32x4 acc2[2][4] = {};            // z' accumulator (rows i*16.., e wave*64..)
    float srow[2][4] = {};            // Sw partials (C-layout rows)
    const int kcol = wave * 16 + tx;  // this lane's k-col within chunk (t-part)

    for (int kc = 0; kc < 32; ++kc) {
        const int kc0 = kc * 64;
        // ---- stage xbT chunk (4 subtiles of 64x64), xb chunk, e chunk ----
#pragma unroll
        for (int l = 0; l < 8; ++l) {
            const int lin = l * 2048 + tid * 8;
            const int q = lin >> 12, r = (lin >> 6) & 63, g = (lin >> 3) & 7;
            gload_lds16(XbT + (size_t)(kc0 + r) * E + q * 64 + ((g ^ (r & 7)) << 3),
                        &xbts[lin]);
        }
#pragma unroll
        for (int l = 0; l < 8; ++l) {
            const int lin = l * 2048 + tid * 8;
            const int r = lin >> 6, g = (lin >> 3) & 7;
            gload_lds16(Xb + (size_t)r * K + kc0 + ((g ^ (r & 7)) << 3),
                        &xbs[lin]);
        }
        {
            const int lin = tid * 8;
            const int r = lin >> 6, g = (lin >> 3) & 7;
            gload_lds16(Ebf + (size_t)(row0 + r) * K + kc0 + ((g ^ (r & 7)) << 3),
                        &es[lin]);
        }
        __syncthreads();

        // ---- t-part: tacc[i] = z(rows i*16..) @ xbT(k-col = kcol) ----
        f32x4 tacc[2] = {};
#pragma unroll
        for (int s = 0; s < 8; ++s) {
            const int g = ((s & 1) * 4 + quad) ^ (kcol & 7);
            const bf16x8 bfr = *(const bf16x8*)&xbts[(s >> 1) * 4096 + kcol * 64 + (g << 3)];
#pragma unroll
            for (int i = 0; i < 2; ++i)
                tacc[i] = __builtin_amdgcn_mfma_f32_16x16x32_bf16(
                    af[i][s], bfr, tacc[i], 0, 0, 0);
        }

        // ---- epilogue: w = e * exp(t*ascale - c2b); into ws; Sw partial ----
        const float cb = c2s[kc0 + kcol];
#pragma unroll
        for (int i = 0; i < 2; ++i)
#pragma unroll
            for (int r = 0; r < 4; ++r) {
                const int prow = i * 16 + quad * 4 + r;
                const int paddr = prow * 64 +
                    (((kcol >> 3) ^ (prow & 7)) << 3) + (kcol & 7);
                const float ev = bf2f(es[paddr]);
                const float wv = ev * __expf(fmaf(tacc[i][r], ascale, -cb));
                srow[i][r] += wv;
                ws[paddr] = f2bf(wv);
            }
        __syncthreads();

        // ---- z-part: acc2 += w(32 x 64k) @ xb^T(e = wave*64..) ----
#pragma unroll
        for (int kk = 0; kk < 2; ++kk) {
            bf16x8 a2[2];
#pragma unroll
            for (int i = 0; i < 2; ++i) {
                const int row = i * 16 + tx;
                a2[i] = *(const bf16x8*)&ws[row * 64 + ((((kk * 4 + quad) ^ (row & 7))) << 3)];
            }
#pragma unroll
            for (int f = 0; f < 4; ++f) {
                const int erow = wave * 64 + f * 16 + tx;
                const bf16x8 b2 = *(const bf16x8*)&xbs[erow * 64 + ((((kk * 4 + quad) ^ (erow & 7))) << 3)];
#pragma unroll
                for (int i = 0; i < 2; ++i)
                    acc2[i][f] = __builtin_amdgcn_mfma_f32_16x16x32_bf16(
                        a2[i], b2, acc2[i][f], 0, 0, 0);
            }
        }
        __syncthreads();
    }

    // ---- Sw: reduce over tx lanes, then across waves via LDS ----
#pragma unroll
    for (int i = 0; i < 2; ++i)
#pragma unroll
        for (int r = 0; r < 4; ++r) {
            float s = srow[i][r];
            s += __shfl_xor(s, 1, 64);
            s += __shfl_xor(s, 2, 64);
            s += __shfl_xor(s, 4, 64);
            s += __shfl_xor(s, 8, 64);
            if (tx == 0) redS[wave][i * 16 + quad * 4 + r] = s;
        }
    __syncthreads();
    float invS[2][4];
#pragma unroll
    for (int i = 0; i < 2; ++i)
#pragma unroll
        for (int r = 0; r < 4; ++r) {
            const int row = i * 16 + quad * 4 + r;
            invS[i][r] = 1.0f / (redS[0][row] + redS[1][row] +
                                 redS[2][row] + redS[3][row]);
        }

    // ---- write z' = acc2/Sw back through LDS (subtile-64), coalesced ----
#pragma unroll
    for (int i = 0; i < 2; ++i)
#pragma unroll
        for (int f = 0; f < 4; ++f)
#pragma unroll
            for (int r = 0; r < 4; ++r) {
                const int row = i * 16 + quad * 4 + r;
                const int e = wave * 64 + f * 16 + tx;
                const int addr = (e >> 6) * 2048 + row * 64 +
                    ((((e >> 3) & 7) ^ (row & 7)) << 3) + (e & 7);
                xbts[addr] = f2bf(acc2[i][f][r] * invS[i][r]);
            }
    __syncthreads();
#pragma unroll
    for (int l = 0; l < 4; ++l) {
        const int lin = l * 2048 + tid * 8;
        const int q = lin >> 11, r = (lin >> 6) & 31, g = (lin >> 3) & 7;
        *(uint4*)(Z + (size_t)(row0 + r) * E + q * 64 + g * 8) =
            *(const uint4*)&xbts[q * 2048 + r * 64 + ((g ^ (r & 7)) << 3)];
    }
}

// ---------------------------------------------------------------------------
// MFMA bf16 GEMM (128x128 tile) with fused MSE-loss epilogue:
// D = P_NULL*exp(x2[row]) + S0[row];
// loss[row] += (1/N)*sum_col (acc/D - X[row,col])^2
// ---------------------------------------------------------------------------
__global__ __launch_bounds__(256) void mfma_loss_kernel(
    const u16* __restrict__ A, const u16* __restrict__ Bm,
    float* __restrict__ loss, const float* __restrict__ x2,
    const float* __restrict__ X, const float* __restrict__ S0,
    int M, int N, int Kd) {
    __shared__ u16 As[128 * 64];
    __shared__ u16 Bs[128 * 64];
    const int tid = threadIdx.x;
    int btr, btc;
    swizzle_tiles(btr, btc);
    const int row0 = btr * 128, col0 = btc * 128;
    const int lane = tid & 63, wave = tid >> 6;
    const int wr = (wave >> 1) * 64, wc = (wave & 1) * 64;
    const int tx = lane & 15, quad = lane >> 4;
    const int txl = tx & 7;

    f32x4 acc[4][4] = {};

    for (int k0 = 0; k0 < Kd; k0 += 64) {
#pragma unroll
        for (int l = 0; l < 4; ++l) {
            const int lin = l * 2048 + tid * 8;
            const int r = lin >> 6;
            const int c = (((lin >> 3) & 7) ^ (r & 7)) * 8;
            gload_lds16(A + (size_t)(row0 + r) * Kd + k0 + c, &As[lin]);
        }
#pragma unroll
        for (int l = 0; l < 4; ++l) {
            const int lin = l * 2048 + tid * 8;
            const int r = lin >> 6;
            const int c = (((lin >> 3) & 7) ^ (r & 7)) * 8;
            gload_lds16(Bm + (size_t)(col0 + r) * Kd + k0 + c, &Bs[lin]);
        }
        __syncthreads();
#pragma unroll
        for (int ks = 0; ks < 2; ++ks) {
            bf16x8 af[4], bfr[4];
            const int gsw = ((ks * 4 + quad) ^ txl) * 8;
#pragma unroll
            for (int i = 0; i < 4; ++i)
                af[i] = *(const bf16x8*)&As[(wr + i * 16 + tx) * 64 + gsw];
#pragma unroll
            for (int j = 0; j < 4; ++j)
                bfr[j] = *(const bf16x8*)&Bs[(wc + j * 16 + tx) * 64 + gsw];
#pragma unroll
            for (int i = 0; i < 4; ++i)
#pragma unroll
                for (int j = 0; j < 4; ++j)
                    acc[i][j] = __builtin_amdgcn_mfma_f32_16x16x32_bf16(
                        af[i], bfr[j], acc[i][j], 0, 0, 0);
        }
        __syncthreads();
    }

    const float inv_n = 1.0f / (float)N;
#pragma unroll
    for (int i = 0; i < 4; ++i) {
#pragma unroll
        for (int r = 0; r < 4; ++r) {
            const int row = row0 + wr + i * 16 + quad * 4 + r;
            const float D = P_NULL * __expf(x2[row]) + S0[row];
            const float invD = 1.0f / D;
            float s = 0.f;
#pragma unroll
            for (int j = 0; j < 4; ++j) {
                const int col = col0 + wc + j * 16 + tx;
                const float d = acc[i][j][r] * invD - X[(size_t)row * N + col];
                s = fmaf(d, d, s);
            }
            s += __shfl_xor(s, 1, 64);
            s += __shfl_xor(s, 2, 64);
            s += __shfl_xor(s, 4, 64);
            s += __shfl_xor(s, 8, 64);
            if (tx == 0) atomicAdd(&loss[row], s * inv_n);
        }
    }
}

// ---------------------------------------------------------------------------
// Row mean of squares of Z (B,E) bf16: x2[row] = mean(Z[row,:]^2)
// ---------------------------------------------------------------------------
__global__ __launch_bounds__(256) void rowmeansq_bf_kernel(
    const u16* __restrict__ Z, float* __restrict__ out) {
    __shared__ float sm[4];
    const float v = bf2f(Z[(size_t)blockIdx.x * E + threadIdx.x]);
    const float s = block_sum256(v * v, sm);
    if (threadIdx.x == 0) out[blockIdx.x] = s * (1.0f / (float)E);
}

// ---------------------------------------------------------------------------
extern "C" void kernel_launch(void* const* d_in, const int* in_sizes, int n_in,
                              void* d_out, int out_size, void* d_ws, size_t ws_size,
                              hipStream_t stream) {
    const float* images = (const float*)d_in[0];  // (B,G)
    const float* xa     = (const float*)d_in[1];  // (G,K)
    const float* xb     = (const float*)d_in[2];  // (E,K)
    float* out = (float*)d_out;                   // (B,)

    // workspace carve-up (u16 elements, all regions 16B-aligned)
    u16* img_bf = (u16*)d_ws;                      // B*G
    u16* xa_bf  = img_bf + (size_t)B * G;          // G*K
    u16* xaT_bf = xa_bf + (size_t)G * K;           // K*G
    u16* xb_bf  = xaT_bf + (size_t)K * G;          // E*K
    u16* xbT_bf = xb_bf + (size_t)E * K;           // K*E
    u16* e_bf   = xbT_bf + (size_t)K * E;          // B*K (unnormalized enc e)
    u16* wu_bf  = e_bf + (size_t)B * K;            // B*K (decode u)
    u16* z_bf   = wu_bf + (size_t)B * K;           // B*E
    float* c2a  = (float*)(z_bf + (size_t)B * E);  // K   --+ one memset
    float* c2b  = c2a + K;                         // K     |
    float* Svec = c2b + K;                         // 2*B --+ (S_enc, S0)
    float* x2z  = Svec + 2 * B;                    // B (fully written)

    (void)hipMemsetAsync(d_out, 0, (size_t)B * sizeof(float), stream);
    (void)hipMemsetAsync(c2a, 0, (size_t)(2 * K + 2 * B) * sizeof(float), stream);

    // prep: bf16 copies + transposes + column mean-squares (one read each)
    f2bf_kernel<<<(B * G) / 2048, 256, 0, stream>>>(images, img_bf, B * G);
    prep_kernel<<<dim3(K / 32, G / 32), 256, 0, stream>>>(
        xa, xa_bf, xaT_bf, c2a, G, K, 1.0f / (float)G);
    prep_kernel<<<dim3(K / 32, E / 32), 256, 0, stream>>>(
        xb, xb_bf, xbT_bf, c2b, E, K, 1.0f / (float)E);

    // encode (softmax eliminated): e = exp(images@xa*(2/G) - c2a), S_enc=rowsum
    float* S_enc = Svec;
    mfma_n64_kernel<EPI_U><<<dim3(K / 64, B / 128), 256, 0, stream>>>(
        img_bf, xaT_bf, e_bf, c2a, nullptr, S_enc, B, K, G, 2.0f / (float)G);

    // z0 = (e @ xb^T) / S_enc[row]   (== pik @ xb^T)
    mfma_z64_kernel<<<dim3(E / 64, B / 64), 256, 0, stream>>>(
        e_bf, xb_bf, z_bf, S_enc, B, E, K);

    // loop: fully fused steps, z updated in place, w never hits HBM
    for (int s = 0; s < N_STEP; ++s) {
        step_kernel<<<B / 32, 256, 0, stream>>>(
            z_bf, xbT_bf, xb_bf, e_bf, c2b);
    }

    // decode: x2 = mean(z^2) ; u = exp(z@xb*(2/E) - c2b) ; S0 = rowsum(u)
    float* S0 = Svec + B;
    rowmeansq_bf_kernel<<<B, 256, 0, stream>>>(z_bf, x2z);
    mfma_n64_kernel<EPI_U><<<dim3(K / 64, B / 128), 256, 0, stream>>>(
        z_bf, xbT_bf, wu_bf, c2b, nullptr, S0, B, K, E, 2.0f / (float)E);

    // loss: recon = (u @ xa^T)/D[row], D = P_NULL*e^{x2}+S0 ;
    // loss[b] = mean_g (recon - images)^2
    mfma_loss_kernel<<<dim3(G / 128, B / 128), 256, 0, stream>>>(
        wu_bf, xa_bf, out, x2z, images, S0, B, G, K);
}